// Round 12
// baseline (204.600 us; speedup 1.0000x reference)
//
#include <hip/hip_runtime.h>
#include <hip/hip_bf16.h>

#define NT 768
#define ND 256
#define PD 128
#define NH 8
#define DH 32
#define NPAIR 589824   // 768*768

// workspace offsets (floats)
#define WS_X     0
#define WS_Q     196608
#define WS_K     393216
#define WS_V     589824
#define WS_GATE  786432
#define WS_AOUT  983040
#define WS_BIAS  1179648   // bias layout: [i][h][j] = (i*8+h)*768+j
// total = 1179648 + 8*589824 = 5898240 floats = 23.6 MB

typedef float f32x4 __attribute__((ext_vector_type(4)));
using bf16x8 = __attribute__((ext_vector_type(8))) short;   // 8 bf16 (4 VGPR)
using f32x4v = __attribute__((ext_vector_type(4))) float;

static __device__ __forceinline__ short f2bf(float f) {
  __hip_bfloat16 h = __float2bfloat16(f);
  union { __hip_bfloat16 h; short s; } u; u.h = h;
  return u.s;
}

// ---------------- K2: LN(node) fused + x @ [w_qkv | w_g] -> q,k,v + gate ----------------
__global__ __launch_bounds__(256) void k_qkvg(const float* __restrict__ node,
                                              const float* __restrict__ lnw,
                                              const float* __restrict__ lnb,
                                              const float* __restrict__ wqkv,
                                              const float* __restrict__ wg,
                                              const float* __restrict__ bg,
                                              float* __restrict__ ws) {
  __shared__ __align__(16) float As[16 * 64];
  __shared__ __align__(16) float Bs[16 * 64];
  __shared__ float MU[64], RS[64];
  __shared__ float LW[256], LB[256];
  int n0 = blockIdx.x * 64, i0 = blockIdx.y * 64, t = threadIdx.x;
  bool isg = (n0 >= 768);
  const float* W = isg ? wg : wqkv;
  int ldb = isg ? 256 : 768;
  int nc0 = isg ? n0 - 768 : n0;
  int tm = t >> 4, tn = t & 15;
  int sm = t >> 2, sk = (t & 3) * 4;
  int bk = t >> 4, bn = (t & 15) * 4;

  LW[t] = lnw[t];
  LB[t] = lnb[t];
  {
    int r = t >> 2, q = t & 3;
    const float4* src = (const float4*)&node[(size_t)(i0 + r) * 256 + q * 64];
    float s1 = 0.f, s2 = 0.f;
#pragma unroll
    for (int c = 0; c < 16; ++c) {
      float4 p = src[c];
      s1 += p.x + p.y + p.z + p.w;
      s2 = fmaf(p.x, p.x, fmaf(p.y, p.y, fmaf(p.z, p.z, fmaf(p.w, p.w, s2))));
    }
    s1 += __shfl_xor(s1, 1); s1 += __shfl_xor(s1, 2);
    s2 += __shfl_xor(s2, 1); s2 += __shfl_xor(s2, 2);
    if (q == 0) {
      float mu = s1 * (1.f / 256.f);
      float var = s2 * (1.f / 256.f) - mu * mu;
      MU[r] = mu;
      RS[r] = rsqrtf(var + 1e-5f);
    }
  }
  __syncthreads();

  float acc[4][4] = {{0.f}};
  for (int k0 = 0; k0 < 256; k0 += 16) {
    float4 av = *(const float4*)&node[(size_t)(i0 + sm) * 256 + k0 + sk];
    float4 bv = *(const float4*)&W[(size_t)(k0 + bk) * ldb + nc0 + bn];
    __syncthreads();
    {
      float mu = MU[sm], rs = RS[sm];
      av.x = (av.x - mu) * rs * LW[k0 + sk + 0] + LB[k0 + sk + 0];
      av.y = (av.y - mu) * rs * LW[k0 + sk + 1] + LB[k0 + sk + 1];
      av.z = (av.z - mu) * rs * LW[k0 + sk + 2] + LB[k0 + sk + 2];
      av.w = (av.w - mu) * rs * LW[k0 + sk + 3] + LB[k0 + sk + 3];
    }
    As[(sk + 0) * 64 + sm] = av.x; As[(sk + 1) * 64 + sm] = av.y;
    As[(sk + 2) * 64 + sm] = av.z; As[(sk + 3) * 64 + sm] = av.w;
    *(float4*)&Bs[bk * 64 + bn] = bv;
    __syncthreads();
#pragma unroll
    for (int kk = 0; kk < 16; ++kk) {
      float4 a4 = *(float4*)&As[kk * 64 + tm * 4];
      float4 b4 = *(float4*)&Bs[kk * 64 + tn * 4];
      float ar[4] = {a4.x, a4.y, a4.z, a4.w};
      float br[4] = {b4.x, b4.y, b4.z, b4.w};
#pragma unroll
      for (int ii = 0; ii < 4; ++ii)
#pragma unroll
        for (int jj = 0; jj < 4; ++jj) acc[ii][jj] = fmaf(ar[ii], br[jj], acc[ii][jj]);
    }
  }
#pragma unroll
  for (int ii = 0; ii < 4; ++ii) {
    int i = i0 + tm * 4 + ii;
#pragma unroll
    for (int jj = 0; jj < 4; ++jj) {
      int o = n0 + tn * 4 + jj;
      float val = acc[ii][jj];
      if (!isg) {
        int which = o >> 8, inner = o & 255, h = inner >> 5, d = inner & 31;
        float* dst = ws + (which == 0 ? WS_Q : (which == 1 ? WS_K : WS_V));
        float sc = (which == 0) ? 0.17677669529663687f : 1.f;  // 1/sqrt(32) on q
        dst[(h * NT + i) * DH + d] = val * sc;
      } else {
        int inner = nc0 + tn * 4 + jj;
        val += bg[inner];
        ws[WS_GATE + i * ND + inner] = 1.f / (1.f + __expf(-val));
      }
    }
  }
}

// ---------------- K3: fused LN(pair) @ w_bias + mask fold -> bias [i][h][j] ----------------
// v11: swapped-operand MFMA, ZERO LDS, zero barriers, zero staging.
// A = [wpt rows 0-7; ones row 8] (M=heads), B = pair columns (N=j, straight
// from global: lane reads 32B contiguous of row j). D[h][j]: col=lane&15=j,
// row=(lane>>4)*4+reg=h. Second MFMA chain on squared B gives s2; ones-row
// gives s1 (D[8][j], lane 32|j). Per-tile: 8 VMEM + cvt + 8 MFMA + 4 stores.
__global__ __launch_bounds__(256) void k_pair_bias(const float* __restrict__ pf,
                                                   const int* __restrict__ mask,
                                                   const float* __restrict__ lnw,
                                                   const float* __restrict__ lnb,
                                                   const float* __restrict__ wb,
                                                   float* __restrict__ bias_out) {
  int t = threadIdx.x;
  int w = t >> 6, l = t & 63;
  int col = l & 15, kg = l >> 4;

  // --- A-frags (wpt^T with ones row 8) + c0/c1, built once per wave ---
  bf16x8 afrag[4];
  float c0p = 0.f, c1p = 0.f;
#pragma unroll
  for (int c = 0; c < 4; ++c) {
#pragma unroll
    for (int e = 0; e < 8; ++e) {
      int k = c * 32 + kg * 8 + e;
      float v = 0.f;
      if (col < 8) {
        float wv = wb[k * 8 + col];
        v = lnw[k] * wv;
        c1p += v;
        c0p = fmaf(lnb[k], wv, c0p);
      } else if (col == 8) {
        v = 1.f;
      }
      afrag[c][e] = f2bf(v);
    }
  }
  // full-k sums for this lane's col (head)
  c1p += __shfl_xor(c1p, 16); c1p += __shfl_xor(c1p, 32);
  c0p += __shfl_xor(c0p, 16); c0p += __shfl_xor(c0p, 32);
  // redistribute: epilogue lane outputs heads h = (l>>4)*4 + r
  float c0h[4], c1h[4];
#pragma unroll
  for (int r = 0; r < 4; ++r) {
    int hh = (kg * 4 + r) & 15;
    c0h[r] = __shfl(c0p, hh);
    c1h[r] = __shfl(c1p, hh);
  }

  size_t wrow0 = ((size_t)blockIdx.x * 4 + w) * 64;   // 64 flat (i,j)-rows per wave
  size_t i8 = (wrow0 / 768) * 8;                      // block never crosses i

#pragma unroll
  for (int tile = 0; tile < 4; ++tile) {
    size_t r0 = wrow0 + tile * 16;
    const float* prow = pf + (r0 + col) * 128;        // this lane's j-row
    // load 32 contiguous floats of the row (this lane's k-slots, all 4 chunks)
    f32x4 lo[4], hi[4];
#pragma unroll
    for (int c = 0; c < 4; ++c) {
      lo[c] = *(const f32x4*)(prow + c * 32 + kg * 8);
      hi[c] = *(const f32x4*)(prow + c * 32 + kg * 8 + 4);
    }
    // convert values + squares to bf16 frags
    f32x4v acc = {0.f, 0.f, 0.f, 0.f};
    f32x4v acc2 = {0.f, 0.f, 0.f, 0.f};
#pragma unroll
    for (int c = 0; c < 4; ++c) {
      bf16x8 bp, bp2;
      f32x4 l2 = lo[c] * lo[c], h2 = hi[c] * hi[c];
#pragma unroll
      for (int e = 0; e < 4; ++e) {
        bp[e] = f2bf(lo[c][e]);  bp[4 + e] = f2bf(hi[c][e]);
        bp2[e] = f2bf(l2[e]);    bp2[4 + e] = f2bf(h2[e]);
      }
      acc = __builtin_amdgcn_mfma_f32_16x16x32_bf16(afrag[c], bp, acc, 0, 0, 0);
      acc2 = __builtin_amdgcn_mfma_f32_16x16x32_bf16(afrag[c], bp2, acc2, 0, 0, 0);
    }
    // s1/s2 from ones-row (D row 8 -> lane 32|j, reg 0)
    float s1 = __shfl(acc[0], 32 | col);
    float s2 = __shfl(acc2[0], 32 | col);
    float mu = s1 * (1.f / 128.f);
    float var = s2 * (1.f / 128.f) - mu * mu;
    float rs = rsqrtf(var + 1e-5f);
    int mk = mask[r0 + col];
    int j = (int)(r0 % 768) + col;
    if (l < 32) {
#pragma unroll
      for (int r = 0; r < 4; ++r) {
        int hh = kg * 4 + r;
        float bv = rs * (acc[r] - mu * c1h[r]) + c0h[r];
        bias_out[(i8 + hh) * 768 + j] = mk ? bv : -1e30f;
      }
    }
  }
}

// ---------------- K4: per (head, 8-row tile) attention + gate ----------------
// 256 threads = 8 rows x 32 lanes. Each wave owns 2 complete rows -> no barriers.
__global__ __launch_bounds__(256) void k_attn(const float* __restrict__ q,
                                              const float* __restrict__ k,
                                              const float* __restrict__ v,
                                              const float* __restrict__ gate,
                                              const float* __restrict__ bias,
                                              float* __restrict__ aout) {
  __shared__ __align__(16) float SIM[8 * 772];
  __shared__ __align__(16) float QS[256];
  int i0 = blockIdx.x * 8, h = blockIdx.y, t = threadIdx.x;
  int tr = t >> 5, tc = t & 31;
  QS[t] = q[((size_t)h * NT + i0 + tr) * DH + tc];   // t == tr*32+tc
  float4 qr[8];
#pragma unroll
  for (int e = 0; e < 8; ++e) qr[e] = *(float4*)&QS[tr * 32 + e * 4];
  const float* Kh = k + (size_t)h * NT * DH;
  const float* Vh = v + (size_t)h * NT * DH;
  const float* brow = bias + ((size_t)(i0 + tr) * 8 + h) * 768;   // [i][h][j]
  float sv[24];
  float mx = -3.4e38f;
#pragma unroll
  for (int it = 0; it < 24; ++it) {
    int j = it * 32 + tc;
    const float4* kr = (const float4*)(Kh + j * DH);
    float s = 0.f;
#pragma unroll
    for (int e = 0; e < 8; ++e) {
      float4 kv = kr[e];
      s += qr[e].x * kv.x + qr[e].y * kv.y + qr[e].z * kv.z + qr[e].w * kv.w;
    }
    s += brow[j];                     // q pre-scaled; bias carries mask fold
    sv[it] = s;
    mx = fmaxf(mx, s);
  }
#pragma unroll
  for (int m = 1; m < 32; m <<= 1) mx = fmaxf(mx, __shfl_xor(mx, m));
  float sum = 0.f;
#pragma unroll
  for (int it = 0; it < 24; ++it) {
    float p = __expf(sv[it] - mx);
    SIM[tr * 772 + it * 32 + tc] = p;
    sum += p;
  }
#pragma unroll
  for (int m = 1; m < 32; m <<= 1) sum += __shfl_xor(sum, m);
  float inv = 1.f / sum;
  float acc = 0.f;
#pragma unroll 8
  for (int j = 0; j < NT; ++j) {
    acc = fmaf(SIM[tr * 772 + j], Vh[j * DH + tc], acc);
  }
  acc *= inv;
  int i = i0 + tr;
  float gg = gate[i * ND + h * DH + tc];
  aout[i * ND + h * DH + tc] = acc * gg;
}

// ---------------- K5: aout @ w_out + b_out -> fp32 output ----------------
__global__ __launch_bounds__(256) void k_proj(const float* __restrict__ a,
                                              const float* __restrict__ w,
                                              const float* __restrict__ b,
                                              float* __restrict__ out) {
  __shared__ __align__(16) float As[16 * 64];
  __shared__ __align__(16) float Bs[16 * 64];
  int n0 = blockIdx.x * 64, i0 = blockIdx.y * 64, t = threadIdx.x;
  int tm = t >> 4, tn = t & 15;
  int sm = t >> 2, sk = (t & 3) * 4;
  int bk = t >> 4, bn = (t & 15) * 4;
  float acc[4][4] = {{0.f}};
  for (int k0 = 0; k0 < 256; k0 += 16) {
    float4 av = *(const float4*)&a[(i0 + sm) * 256 + k0 + sk];
    float4 bv = *(const float4*)&w[(k0 + bk) * 256 + n0 + bn];
    __syncthreads();
    As[(sk + 0) * 64 + sm] = av.x; As[(sk + 1) * 64 + sm] = av.y;
    As[(sk + 2) * 64 + sm] = av.z; As[(sk + 3) * 64 + sm] = av.w;
    *(float4*)&Bs[bk * 64 + bn] = bv;
    __syncthreads();
#pragma unroll
    for (int kk = 0; kk < 16; ++kk) {
      float4 a4 = *(float4*)&As[kk * 64 + tm * 4];
      float4 b4 = *(float4*)&Bs[kk * 64 + tn * 4];
      float ar[4] = {a4.x, a4.y, a4.z, a4.w};
      float br[4] = {b4.x, b4.y, b4.z, b4.w};
#pragma unroll
      for (int ii = 0; ii < 4; ++ii)
#pragma unroll
        for (int jj = 0; jj < 4; ++jj) acc[ii][jj] = fmaf(ar[ii], br[jj], acc[ii][jj]);
    }
  }
#pragma unroll
  for (int ii = 0; ii < 4; ++ii) {
    int i = i0 + tm * 4 + ii;
#pragma unroll
    for (int jj = 0; jj < 4; ++jj) {
      int o = n0 + tn * 4 + jj;
      out[i * 256 + o] = acc[ii][jj] + b[o];
    }
  }
}

extern "C" void kernel_launch(void* const* d_in, const int* in_sizes, int n_in,
                              void* d_out, int out_size, void* d_ws, size_t ws_size,
                              hipStream_t stream) {
  const float* node   = (const float*)d_in[0];
  const float* pair   = (const float*)d_in[1];
  const int*   mask   = (const int*)d_in[2];
  const float* ln_nw  = (const float*)d_in[3];
  const float* ln_nb  = (const float*)d_in[4];
  const float* ln_pw  = (const float*)d_in[5];
  const float* ln_pb  = (const float*)d_in[6];
  const float* w_qkv  = (const float*)d_in[7];
  const float* w_g    = (const float*)d_in[8];
  const float* b_g    = (const float*)d_in[9];
  const float* w_bias = (const float*)d_in[10];
  const float* w_out  = (const float*)d_in[11];
  const float* b_out  = (const float*)d_in[12];
  float* ws = (float*)d_ws;
  float* out = (float*)d_out;

  k_pair_bias<<<NPAIR / 256, 256, 0, stream>>>(pair, mask, ln_pw, ln_pb, w_bias,
                                               ws + WS_BIAS);
  k_qkvg<<<dim3(16, 12), 256, 0, stream>>>(node, ln_nw, ln_nb, w_qkv, w_g, b_g, ws);
  k_attn<<<dim3(96, 8), 256, 0, stream>>>(ws + WS_Q, ws + WS_K, ws + WS_V,
                                          ws + WS_GATE, ws + WS_BIAS, ws + WS_AOUT);
  k_proj<<<dim3(4, 12), 256, 0, stream>>>(ws + WS_AOUT, w_out, b_out, out);
}